// Round 1
// 262.332 us; speedup vs baseline: 1.0680x; 1.0680x over previous
//
#include <hip/hip_runtime.h>
#include <hip/hip_bf16.h>
#include <hip/hip_fp16.h>

// Problem constants
#define B_N 32
#define S_N 2048
#define E_N 256
#define H_N 256
#define K2_N 512            // 2E
#define N3_N 768            // 3H
#define M_N (B_N * S_N)     // 65536 rows
#define CCH 64              // scan chunks per sequence (R8: 16->64 for occupancy)
#define LCH (S_N / CCH)     // 32 steps per chunk

typedef __hip_bfloat16 bf16;
typedef __attribute__((ext_vector_type(8))) short bf16x8s;
typedef __attribute__((ext_vector_type(4))) float f32x4;

#define BM 128
#define BN 128
#define BK 32

#define GLOBAL_AS __attribute__((address_space(1)))
#define LDS_AS    __attribute__((address_space(3)))

// R7 post-mortem: PASS 280.7us, gemm_act 127us @ 402TF. MfmaUtil 16.5%,
// VALUBusy 32%, BANK_CONFLICT 6.29M/dispatch. Diagnosis: (a) IEEE fdiv in
// sigmoid/tanh epilogue (~10 instr each, 64/thread) rivals the whole K-loop
// MFMA budget; (b) 64B LDS rows -> 8-way bank conflict on ds_read_b128
// (~8% of cycles). R8: (1) rcp-based activations; (2) T2 XOR slot swizzle,
// linear LDS dest + swizzled GLOBAL source + swizzled read (guide rule #21);
// (3) CCH 16->64 so scan_part1/3 reach full occupancy (512->2048 blocks).

__device__ __forceinline__ float sigmoid_fast(float v) {
    // v_exp + v_add + v_rcp (approx rcp: ~1ulp, negligible vs bf16 storage)
    return __builtin_amdgcn_rcpf(1.0f + __expf(-v));
}
__device__ __forceinline__ float tanh_fast(float v) {
    return 2.0f * __builtin_amdgcn_rcpf(1.0f + __expf(-2.0f * v)) - 1.0f;
}

// K0a: x fp32 -> xb bf16; also zeroes the 256-element guard row before xb
// (so x_prev reads at r==-1 see zeros).
__global__ __launch_bounds__(256) void convert_x(
    const float* __restrict__ x, bf16* __restrict__ xb)
{
    if (blockIdx.x == 0 && threadIdx.x < 32) {
        bf16 z[8] = {};
        *(int4*)(xb - 256 + threadIdx.x * 8) = *(int4*)z;
    }
    size_t i = ((size_t)blockIdx.x * 256 + threadIdx.x) * 8;
    float4 v0 = *(const float4*)(x + i);
    float4 v1 = *(const float4*)(x + i + 4);
    bf16 t[8];
    t[0] = __float2bfloat16(v0.x); t[1] = __float2bfloat16(v0.y);
    t[2] = __float2bfloat16(v0.z); t[3] = __float2bfloat16(v0.w);
    t[4] = __float2bfloat16(v1.x); t[5] = __float2bfloat16(v1.y);
    t[6] = __float2bfloat16(v1.z); t[7] = __float2bfloat16(v1.w);
    *(int4*)(xb + i) = *(int4*)t;
}

// K0b: W fp32 [512][768] -> Wt bf16 [768][512] via LDS 64x64 tile transpose.
__global__ __launch_bounds__(256) void transpose_w(
    const float* __restrict__ W, bf16* __restrict__ Wt)
{
    __shared__ bf16 tile[64][65];
    const int k0 = blockIdx.x * 64;          // 0..448
    const int n0 = blockIdx.y * 64;          // 0..704
    const int t  = threadIdx.x;
    const int tr = t >> 6;                   // 0..3
    const int tc = t & 63;
    #pragma unroll
    for (int p = 0; p < 16; ++p) {
        int kk = tr + p * 4;
        tile[kk][tc] = __float2bfloat16(W[(size_t)(k0 + kk) * N3_N + n0 + tc]);
    }
    __syncthreads();
    #pragma unroll
    for (int p = 0; p < 16; ++p) {
        int nn = tr + p * 4;
        Wt[(size_t)(n0 + nn) * K2_N + k0 + tc] = tile[tc][nn];
    }
}

// K1: gates GEMM (m97-style async staging) + bias + activation.
// z -> bf16 ws, f -> fp16 ws, o -> fp32 out (hidden_temp region).
//
// LDS layout (R8): logical tile row r, 16B slot s lives at PHYSICAL slot
// s ^ ((r>>1)&3). global_load_lds dest stays linear (HW requirement, m104);
// the permutation is applied on the GLOBAL source address at stage time and
// on the ds_read address at use time (same involution both sides, rule #21).
// Spreads each 16-lane quad group across all 32 banks (was 8-way conflict).
__global__ __launch_bounds__(256) void gemm_act(
    const bf16* __restrict__ xb, const bf16* __restrict__ Wt,
    const float* __restrict__ bvec,
    bf16* __restrict__ Zp, __half* __restrict__ Fh, float* __restrict__ Oout)
{
    __shared__ bf16 As[BM][BK];   // unpadded: global_load_lds needs lane-contiguous dest
    __shared__ bf16 Bs[BN][BK];

    const int tid  = threadIdx.x;
    const int lane = tid & 63;
    const int wave = tid >> 6;
    const int wm   = (wave & 1) * 64;
    const int wn   = (wave >> 1) * 64;
    const int l15  = lane & 15;
    const int quad = lane >> 4;
    const int l4   = lane >> 2;      // chunk row 0..15
    const int q4   = lane & 3;       // k-quarter 0..3
    const int gq   = q4 ^ ((l4 >> 1) & 3);    // swizzled source slot (stage)
    const int swq  = quad ^ ((l15 >> 1) & 3); // swizzled slot (fragment read)
    const int r0   = blockIdx.x * BM;
    const int n0   = blockIdx.y * BN;
    const bool zfix = ((r0 & (S_N - 1)) == 0);  // block row 0 has s==0

    f32x4 acc[4][4] = {};

    for (int kt = 0; kt < K2_N / BK; ++kt) {
        const int k0 = kt * BK;
        const bool second = (k0 >= E_N);   // x_{t-1} half
        __syncthreads();
        // --- async global->LDS staging: each wave 2 A-chunks + 2 B-chunks ---
        // chunk c = 16 rows x 32 k = 1 KiB; lane l -> row c*16+l/4, phys slot l%4.
        // Source slot pre-swizzled so phys slot q4 holds logical slot q4^f(row).
        #pragma unroll
        for (int cc = 0; cc < 2; ++cc) {
            int c   = wave + cc * 4;
            int row = c * 16 + l4;
            int rA  = r0 + row - (second ? 1 : 0);
            const bf16* ga = xb + (size_t)rA * E_N + (k0 & (E_N - 1)) + gq * 8;
            __builtin_amdgcn_global_load_lds(
                (const GLOBAL_AS void*)ga,
                (LDS_AS void*)&As[c * 16][0], 16, 0, 0);
            const bf16* gb = Wt + (size_t)(n0 + row) * K2_N + k0 + gq * 8;
            __builtin_amdgcn_global_load_lds(
                (const GLOBAL_AS void*)gb,
                (LDS_AS void*)&Bs[c * 16][0], 16, 0, 0);
        }
        __syncthreads();
        if (second && zfix) {
            // global row r0 has s==0: x_prev must be zero (we staged xb[r0-1]).
            // Row 0's swizzle f(0)==0, so a linear zero-fill is still correct.
            if (tid < 4) {
                bf16 zz[8] = {};
                *(int4*)(&As[0][tid * 8]) = *(int4*)zz;
            }
            __syncthreads();
        }
        // --- fragments + MFMA (canonical orientation, HW-confirmed R6) ---
        bf16x8s a_frag[4], b_frag[4];
        #pragma unroll
        for (int mi = 0; mi < 4; ++mi)
            a_frag[mi] = *(const bf16x8s*)(&As[wm + mi * 16 + l15][swq * 8]);
        #pragma unroll
        for (int ni = 0; ni < 4; ++ni)
            b_frag[ni] = *(const bf16x8s*)(&Bs[wn + ni * 16 + l15][swq * 8]);
        #pragma unroll
        for (int mi = 0; mi < 4; ++mi)
            #pragma unroll
            for (int ni = 0; ni < 4; ++ni)
                acc[mi][ni] = __builtin_amdgcn_mfma_f32_16x16x32_bf16(
                    a_frag[mi], b_frag[ni], acc[mi][ni], 0, 0, 0);
    }

    // --- epilogue: D row = quad*4+reg (x-row), D col = l15 (gate col) ---
    const int type = n0 >> 8;                 // 0=z(tanh), 1=f(sig), 2=o(sig)
    #pragma unroll
    for (int ni = 0; ni < 4; ++ni) {
        int colg = n0 + wn + ni * 16 + l15;
        int col  = colg - type * 256;
        float bias = bvec[colg];
        #pragma unroll
        for (int mi = 0; mi < 4; ++mi) {
            #pragma unroll
            for (int j = 0; j < 4; ++j) {
                int r = r0 + wm + mi * 16 + quad * 4 + j;
                float v = acc[mi][ni][j] + bias;
                if (type == 0)
                    Zp[(size_t)r * H_N + col] = __float2bfloat16(tanh_fast(v));
                else if (type == 1)
                    Fh[(size_t)r * H_N + col] = __float2half(sigmoid_fast(v));
                else
                    Oout[(size_t)r * H_N + col] = sigmoid_fast(v);
            }
        }
    }
}

// K2: per-chunk local scan from c=0
__global__ __launch_bounds__(256) void scan_part1(
    const bf16* __restrict__ Zp, const __half* __restrict__ Fh,
    float* __restrict__ Cend, float* __restrict__ Pprod)
{
    int bc = blockIdx.x;
    int h  = threadIdx.x;
    size_t base = (size_t)bc * LCH * H_N + h;
    float c = 0.f, P = 1.f;
    for (int t = 0; t < LCH; ++t) {
        float z = __bfloat162float(Zp[base]);
        float f = __half2float(Fh[base]);
        c = f * c + (1.f - f) * z;
        P *= f;
        base += H_N;
    }
    Cend[(size_t)bc * H_N + h]  = c;
    Pprod[(size_t)bc * H_N + h] = P;
}

// K3: sequential scan across chunks
__global__ __launch_bounds__(256) void scan_part2(
    const float* __restrict__ Cend, const float* __restrict__ Pprod,
    float* __restrict__ Cstart)
{
    int b = blockIdx.x;
    int h = threadIdx.x;
    float cs = 0.f;
    for (int ch = 0; ch < CCH; ++ch) {
        size_t idx = (size_t)(b * CCH + ch) * H_N + h;
        Cstart[idx] = cs;
        cs = Cend[idx] + Pprod[idx] * cs;
    }
}

// K4: replay chunk; o staged fp32 in outH, overwritten with fp32 h in-place.
__global__ __launch_bounds__(256) void scan_part3(
    const bf16* __restrict__ Zp, const __half* __restrict__ Fh,
    const float* __restrict__ Cstart, const int* __restrict__ mask,
    float* __restrict__ outH, float* __restrict__ outHid, float* __restrict__ outCell)
{
    int bc = blockIdx.x;
    int b  = bc / CCH;
    int h  = threadIdx.x;
    float c = Cstart[(size_t)bc * H_N + h];
    int tgt = mask[b] - 1;
    tgt = (tgt < 0) ? 0 : ((tgt > S_N - 1) ? (S_N - 1) : tgt);
    int s0 = (bc & (CCH - 1)) * LCH;
    size_t base = (size_t)bc * LCH * H_N + h;
    for (int t = 0; t < LCH; ++t) {
        float z = __bfloat162float(Zp[base]);
        float f = __half2float(Fh[base]);
        float o = outH[base];
        c = f * c + (1.f - f) * z;
        float hv = o * c;
        outH[base] = hv;
        if (s0 + t == tgt) {
            outHid[(size_t)b * H_N + h]  = hv;
            outCell[(size_t)b * H_N + h] = c;
        }
        base += H_N;
    }
}

extern "C" void kernel_launch(void* const* d_in, const int* in_sizes, int n_in,
                              void* d_out, int out_size, void* d_ws, size_t ws_size,
                              hipStream_t stream) {
    // Resolve inputs by element count: x=16777216, mask=32, W=393216, b=768.
    const float* x = nullptr; const int* mask = nullptr;
    const float* W = nullptr; const float* bvec = nullptr;
    for (int i = 0; i < n_in; ++i) {
        switch (in_sizes[i]) {
            case M_N * E_N:     x    = (const float*)d_in[i]; break;
            case B_N:           mask = (const int*)d_in[i]; break;
            case K2_N * N3_N:   W    = (const float*)d_in[i]; break;
            case N3_N:          bvec = (const float*)d_in[i]; break;
        }
    }

    float* out     = (float*)d_out;                     // hidden_temp [B,S,H] fp32 (o staging)
    float* outHid  = out + (size_t)M_N * H_N;           // hidden [B,1,H]
    float* outCell = outHid + (size_t)B_N * H_N;        // cell_state [B,1,H]

    // ws layout (~103 MiB; ws >= 129.5 MiB proven R2/R3 identity):
    // [512B guard][xb 32MiB][Wt 0.75MiB][Zp 32MiB][Fh 32MiB][state 6MiB]
    bf16*   xb = (bf16*)d_ws + 256;                     // guard row before xb
    bf16*   Wt = xb + (size_t)M_N * E_N;
    bf16*   Zp = Wt + (size_t)N3_N * K2_N;
    __half* Fh = (__half*)(Zp + (size_t)M_N * H_N);
    float* Cend   = (float*)(Fh + (size_t)M_N * H_N);
    float* Pprod  = Cend + (size_t)B_N * CCH * H_N;
    float* Cstart = Pprod + (size_t)B_N * CCH * H_N;

    convert_x<<<M_N * E_N / (256 * 8), 256, 0, stream>>>(x, xb);
    transpose_w<<<dim3(K2_N / 64, N3_N / 64), 256, 0, stream>>>(W, Wt);

    dim3 g1(M_N / BM, N3_N / BN);   // 512 x 6
    gemm_act<<<g1, 256, 0, stream>>>(xb, Wt, bvec, Zp, Fh, out);
    scan_part1<<<B_N * CCH, 256, 0, stream>>>(Zp, Fh, Cend, Pprod);
    scan_part2<<<B_N, 256, 0, stream>>>(Cend, Pprod, Cstart);
    scan_part3<<<B_N * CCH, 256, 0, stream>>>(Zp, Fh, Cstart, mask, out, outHid, outCell);
}